// Round 23
// baseline (370.730 us; speedup 1.0000x reference)
//
#include <hip/hip_runtime.h>

// Soft-DTW, gamma=1.0, B=64, N=M=1024. Linear-weight cells + integer-exponent
// scale tracking (R15-R20 numerics, proven absmax 0.0).
// R23 = R20 main structure + LAYOUT PRE-PASS:
//   prepass kernel writes Dp[job][strip t][quad p][row r][col k] =
//   exp2(-D[b][4p+r][q*512+t*8+k] * log2e)  -- i.e. the per-cell factor f,
//   stored so each lane's per-iteration 128B (4 rows x 8 cols) is ONE
//   aligned 128B line. Main kernel: 64 line-touches/iter (was 256) and no
//   in-loop exp2 (was 32 quarter-rate trans ops). Mailbox/anchor/shfl logic
//   is R20-verbatim (poison protocol, 8-deep consumer prefetch ring).
// Workspace: [mailbox 256KB][Dp 256MB]; falls back to the proven R20 kernel
// if ws_size is too small.

#define LOG2E 1.4426950408889634f
#define LN2  0.6931471805599453f

constexpr int N = 1024;
constexpr int TPB = 64;              // one wave per block (main)
constexpr int KC = 8;                // columns per thread (panel = 512 cols)
constexpr int RQ = 4;                // rows per iteration (quad)
constexpr int NQ = N / RQ;           // 256 quads
constexpr int NPAN = 2;
constexpr int PC = N / NPAN;         // 512 columns per panel
constexpr int ITER = 320;            // last real iteration: 255 + 63 = 318
constexpr unsigned long long POISON = 0xFFFFFFFFFFFFFFFFull;

constexpr int STRIP_FLOATS = NQ * 32;            // 8192 floats = 32KB per strip
constexpr int JOB_FLOATS   = 64 * STRIP_FLOATS;  // 2MB per job (64 strips)
constexpr size_t MBOX_BYTES = (size_t)64 * NQ * 2 * sizeof(unsigned long long); // 256KB
constexpr size_t DP_BYTES   = (size_t)128 * JOB_FLOATS * sizeof(float);         // 256MB

__device__ __forceinline__ float fexp2(float x){float r;asm("v_exp_f32 %0, %1":"=v"(r):"v"(x));return r;}
__device__ __forceinline__ float flog2(float x){float r;asm("v_log_f32 %0, %1":"=v"(r):"v"(x));return r;}
__device__ __forceinline__ int   ffrexpe(float x){int r;asm("v_frexp_exp_i32_f32 %0, %1":"=v"(r):"v"(x));return r;}
__device__ __forceinline__ float fldexp(float x, int e){float r;asm("v_ldexp_f32 %0, %1, %2":"=v"(r):"v"(x),"v"(e));return r;}
__device__ __forceinline__ unsigned long long packv(float a, float b){
    return ((unsigned long long)__float_as_uint(b) << 32) | __float_as_uint(a);
}
__device__ __forceinline__ unsigned long long ldrelax(const unsigned long long* p){
    return __hip_atomic_load(p, __ATOMIC_RELAXED, __HIP_MEMORY_SCOPE_AGENT);
}

// ===================== PRE-PASS: skewed re-layout + f =====================
// grid: job(128) x strip-group g(16, 4 strips=32 cols) x row-block rb(8, 128 rows)
// blockIdx.x = job*128 + g*8 + rb ; 256 threads.
__global__ __launch_bounds__(256)
void prepass_kernel(const float* __restrict__ D, float* __restrict__ Dp){
    const int blk = blockIdx.x;
    const int rb  = blk & 7;
    const int g   = (blk >> 3) & 15;
    const int job = blk >> 7;
    const int b = job & 63, q = job >> 6;
    const int tid = threadIdx.x;

    __shared__ float lds[128 * 33];

    // read 128 rows x 32 cols (coalesced, f computed on the fly)
    {
        const int row  = tid >> 1;          // 0..127
        const int half = tid & 1;           // 0..1 (16 cols each)
        const float* src = D + (size_t)b * N * N + (size_t)(rb * 128 + row) * N
                         + q * PC + g * 32 + half * 16;
        float4 v0 = *(const float4*)(src + 0);
        float4 v1 = *(const float4*)(src + 4);
        float4 v2 = *(const float4*)(src + 8);
        float4 v3 = *(const float4*)(src + 12);
        float* l = &lds[row * 33 + half * 16];
        l[0]  = fexp2(-LOG2E * v0.x); l[1]  = fexp2(-LOG2E * v0.y);
        l[2]  = fexp2(-LOG2E * v0.z); l[3]  = fexp2(-LOG2E * v0.w);
        l[4]  = fexp2(-LOG2E * v1.x); l[5]  = fexp2(-LOG2E * v1.y);
        l[6]  = fexp2(-LOG2E * v1.z); l[7]  = fexp2(-LOG2E * v1.w);
        l[8]  = fexp2(-LOG2E * v2.x); l[9]  = fexp2(-LOG2E * v2.y);
        l[10] = fexp2(-LOG2E * v2.z); l[11] = fexp2(-LOG2E * v2.w);
        l[12] = fexp2(-LOG2E * v3.x); l[13] = fexp2(-LOG2E * v3.y);
        l[14] = fexp2(-LOG2E * v3.z); l[15] = fexp2(-LOG2E * v3.w);
    }
    __syncthreads();

    // write 4 strips x 32 quads x 128B (coalesced within each strip)
    {
        const int u    = tid >> 1;          // 0..127: s = u>>5, p_loc = u&31
        const int half = tid & 1;           // rows 2*half..2*half+1 of the quad
        const int s    = u >> 5;
        const int pl   = u & 31;
        float o[16];
#pragma unroll
        for (int r2 = 0; r2 < 2; ++r2)
#pragma unroll
            for (int k = 0; k < 8; ++k)
                o[r2 * 8 + k] = lds[(4 * pl + 2 * half + r2) * 33 + s * 8 + k];
        float* dst = Dp + (size_t)job * JOB_FLOATS
                   + (size_t)(g * 4 + s) * STRIP_FLOATS
                   + (size_t)(rb * 32 + pl) * 32 + half * 16;
        *(float4*)(dst + 0)  = make_float4(o[0], o[1], o[2], o[3]);
        *(float4*)(dst + 4)  = make_float4(o[4], o[5], o[6], o[7]);
        *(float4*)(dst + 8)  = make_float4(o[8], o[9], o[10], o[11]);
        *(float4*)(dst + 12) = make_float4(o[12], o[13], o[14], o[15]);
    }
}

// ===================== MAIN (coalesced f, R20 protocol) =====================
__global__ __launch_bounds__(TPB, 1)
void softdtw_kernel(const float* __restrict__ Dp, float* __restrict__ out,
                    unsigned long long* __restrict__ pay){
    const int blk = blockIdx.x;
    const int b = blk & 63;              // batch
    const int q = blk >> 6;              // panel (0 or 1)
    const int t = threadIdx.x;
    const float* __restrict__ sp = Dp + (size_t)(q * 64 + b) * JOB_FLOATS
                                 + (size_t)t * STRIP_FLOATS;

    const bool isProd = (t == TPB - 1) && (q == 0);
    const bool isCons = (t == 0) && (q == 1);
    const size_t base = (size_t)b * NQ * 2;

    float pW[KC] = {0,0,0,0,0,0,0,0};
    int   S = 0;
    float luW = (t == 0 && q == 0) ? 1.0f : 0.0f;
    float exW[RQ] = {0,0,0,0};
    int   exS = 0;
    float nW[RQ] = {0,0,0,0};
    int   nS = 0;

    unsigned long long rg[8][2];
#pragma unroll
    for (int i = 0; i < 8; ++i) { rg[i][0] = POISON; rg[i][1] = POISON; }
    if (isCons) {
#pragma unroll
        for (int i = 0; i < 8; ++i) {
            rg[i][0] = ldrelax(&pay[base + (size_t)i * 2 + 0]);
            rg[i][1] = ldrelax(&pay[base + (size_t)i * 2 + 1]);
        }
    }

    float4 ld[2][8];                     // 2 slots x 128B (one line per iter)
#pragma unroll
    for (int x = 0; x < 2; ++x) {
        int pc = min(max(x - t, 0), NQ - 1);
        const float* a = sp + (size_t)pc * 32;
#pragma unroll
        for (int h = 0; h < 8; ++h) ld[x][h] = *(const float4*)(a + 4 * h);
    }
    __builtin_amdgcn_sched_barrier(0);

    for (int jb = 0; jb < ITER; jb += 8) {
#pragma unroll
        for (int u = 0; u < 8; ++u) {
            const int p = jb + u - t;
            const bool active = (unsigned)p < (unsigned)NQ;
            const int slot = u & 1;

            float cv0 = 0, cv1 = 0, cv2 = 0, cv3 = 0;
            if (isCons && active) {
                unsigned long long w0 = rg[u][0];
                unsigned long long w1 = rg[u][1];
                while (w0 == POISON) w0 = ldrelax(&pay[base + (size_t)p * 2 + 0]);
                while (w1 == POISON) w1 = ldrelax(&pay[base + (size_t)p * 2 + 1]);
                cv0 = __uint_as_float((unsigned)(w0 & 0xFFFFFFFFu));
                cv1 = __uint_as_float((unsigned)(w0 >> 32));
                cv2 = __uint_as_float((unsigned)(w1 & 0xFFFFFFFFu));
                cv3 = __uint_as_float((unsigned)(w1 >> 32));
            }

            const int iS = nS;
            if (p == 0) {
                if (isCons) S = (int)(0.0f - cv0);
                else if (t == 0 && q == 0) S = 0;
                else S = iS;
            }

            float eW[RQ];
            {
                const int dS = iS - S;
                eW[0] = fldexp(nW[0], dS); eW[1] = fldexp(nW[1], dS);
                eW[2] = fldexp(nW[2], dS); eW[3] = fldexp(nW[3], dS);
            }
            if (t == 0 && q == 0) { eW[0] = eW[1] = eW[2] = eW[3] = 0.0f; }
            if (isCons) {
                const float Sf = (float)S;
                eW[0] = fexp2(0.0f - cv0 - Sf);
                eW[1] = fexp2(0.0f - cv1 - Sf);
                eW[2] = fexp2(0.0f - cv2 - Sf);
                eW[3] = fexp2(0.0f - cv3 - Sf);
            }

            // ---- 32 cells: W = f*(up + diag + left); f preloaded ----
            float a0 = pW[0], a1 = pW[1], a2 = pW[2], a3 = pW[3];
            float a4 = pW[4], a5 = pW[5], a6 = pW[6], a7 = pW[7];
            float dg = luW;
            float eR[RQ];
#pragma unroll
            for (int r = 0; r < RQ; ++r) {
                const float4 fa = ld[slot][r * 2 + 0];
                const float4 fb = ld[slot][r * 2 + 1];
                float s01 = a0 + a1, s12 = a1 + a2, s23 = a2 + a3, s34 = a3 + a4;
                float s45 = a4 + a5, s56 = a5 + a6, s67 = a6 + a7;
                float t0 = dg + eW[r];
                float W0 = fa.x * (a0 + t0);
                float W1 = fa.y * (s01 + W0);
                float W2 = fa.z * (s12 + W1);
                float W3 = fa.w * (s23 + W2);
                float W4 = fb.x * (s34 + W3);
                float W5 = fb.y * (s45 + W4);
                float W6 = fb.z * (s56 + W5);
                float W7 = fb.w * (s67 + W6);
                eR[r] = W7;
                dg = eW[r];
                a0 = W0; a1 = W1; a2 = W2; a3 = W3;
                a4 = W4; a5 = W5; a6 = W6; a7 = W7;
            }

            const int e = ffrexpe(a7);
            const float sc = fldexp(1.0f, -e);

            if (active) {
                pW[0] = a0 * sc; pW[1] = a1 * sc; pW[2] = a2 * sc; pW[3] = a3 * sc;
                pW[4] = a4 * sc; pW[5] = a5 * sc; pW[6] = a6 * sc; pW[7] = a7 * sc;
                luW = dg * sc;
                exW[0] = eR[0] * sc; exW[1] = eR[1] * sc;
                exW[2] = eR[2] * sc; exW[3] = eR[3] * sc;
                S += e; exS = S;
            }

            if (isProd && active) {
                const float Sf = (float)S;
                float v0 = 0.0f - (flog2(exW[0]) + Sf);
                float v1 = 0.0f - (flog2(exW[1]) + Sf);
                float v2 = 0.0f - (flog2(exW[2]) + Sf);
                float v3 = 0.0f - (flog2(exW[3]) + Sf);
                __hip_atomic_store(&pay[base + (size_t)p * 2 + 0], packv(v0, v1), __ATOMIC_RELAXED, __HIP_MEMORY_SCOPE_AGENT);
                __hip_atomic_store(&pay[base + (size_t)p * 2 + 1], packv(v2, v3), __ATOMIC_RELAXED, __HIP_MEMORY_SCOPE_AGENT);
            }

            // D' loads for iteration j+2 (one 128B line)
            {
                int pc = min(max(p + 2, 0), NQ - 1);
                const float* a = sp + (size_t)pc * 32;
#pragma unroll
                for (int h = 0; h < 8; ++h) ld[slot][h] = *(const float4*)(a + 4 * h);
            }
            __builtin_amdgcn_sched_barrier(0);

            if (isCons && (p + 8) < NQ) {
                rg[u][0] = ldrelax(&pay[base + (size_t)(p + 8) * 2 + 0]);
                rg[u][1] = ldrelax(&pay[base + (size_t)(p + 8) * 2 + 1]);
            }

            nW[0] = __shfl_up(exW[0], 1);
            nW[1] = __shfl_up(exW[1], 1);
            nW[2] = __shfl_up(exW[2], 1);
            nW[3] = __shfl_up(exW[3], 1);
            nS    = __shfl_up(exS, 1);
        }
    }

    if (q == NPAN - 1 && t == TPB - 1)
        out[b] = -(flog2(pW[KC - 1]) + (float)S) * LN2;
}

// ===================== FALLBACK (R20 verbatim, proven 254us) =====================
__global__ __launch_bounds__(TPB, 1)
void softdtw_fb(const float* __restrict__ D, float* __restrict__ out,
                unsigned long long* __restrict__ pay){
    const int blk = blockIdx.x;
    const int b = blk & 63, q = blk >> 6;
    const int t = threadIdx.x;
    const float* __restrict__ bp = D + (size_t)b * N * N + q * PC + t * KC;
    const bool isProd = (t == TPB - 1) && (q == 0);
    const bool isCons = (t == 0) && (q == 1);
    const size_t base = (size_t)b * NQ * 2;
    float pW[KC] = {0,0,0,0,0,0,0,0};
    int S = 0; float luW = (t == 0 && q == 0) ? 1.0f : 0.0f;
    float exW[RQ] = {0,0,0,0}; int exS = 0;
    float nW[RQ] = {0,0,0,0}; int nS = 0;
    unsigned long long rg[8][2];
#pragma unroll
    for (int i = 0; i < 8; ++i) { rg[i][0] = POISON; rg[i][1] = POISON; }
    if (isCons) {
#pragma unroll
        for (int i = 0; i < 8; ++i) {
            rg[i][0] = ldrelax(&pay[base + (size_t)i * 2 + 0]);
            rg[i][1] = ldrelax(&pay[base + (size_t)i * 2 + 1]);
        }
    }
    float4 ld[2][RQ][2];
#pragma unroll
    for (int x = 0; x < 2; ++x) {
        int pc = min(max(x - t, 0), NQ - 1);
        const float* a = bp + (size_t)(pc * RQ) * N;
#pragma unroll
        for (int r = 0; r < RQ; ++r) { ld[x][r][0] = *(const float4*)(a + (size_t)r * N); ld[x][r][1] = *(const float4*)(a + (size_t)r * N + 4); }
    }
    __builtin_amdgcn_sched_barrier(0);
    for (int jb = 0; jb < ITER; jb += 8) {
#pragma unroll
        for (int u = 0; u < 8; ++u) {
            const int p = jb + u - t;
            const bool active = (unsigned)p < (unsigned)NQ;
            const int slot = u & 1;
            float cv0 = 0, cv1 = 0, cv2 = 0, cv3 = 0;
            if (isCons && active) {
                unsigned long long w0 = rg[u][0], w1 = rg[u][1];
                while (w0 == POISON) w0 = ldrelax(&pay[base + (size_t)p * 2 + 0]);
                while (w1 == POISON) w1 = ldrelax(&pay[base + (size_t)p * 2 + 1]);
                cv0 = __uint_as_float((unsigned)(w0 & 0xFFFFFFFFu));
                cv1 = __uint_as_float((unsigned)(w0 >> 32));
                cv2 = __uint_as_float((unsigned)(w1 & 0xFFFFFFFFu));
                cv3 = __uint_as_float((unsigned)(w1 >> 32));
            }
            const int iS = nS;
            if (p == 0) { if (isCons) S = (int)(0.0f - cv0); else if (t == 0 && q == 0) S = 0; else S = iS; }
            float eW[RQ];
            { const int dS = iS - S;
              eW[0] = fldexp(nW[0], dS); eW[1] = fldexp(nW[1], dS);
              eW[2] = fldexp(nW[2], dS); eW[3] = fldexp(nW[3], dS); }
            if (t == 0 && q == 0) { eW[0] = eW[1] = eW[2] = eW[3] = 0.0f; }
            if (isCons) {
                const float Sf = (float)S;
                eW[0] = fexp2(0.0f - cv0 - Sf); eW[1] = fexp2(0.0f - cv1 - Sf);
                eW[2] = fexp2(0.0f - cv2 - Sf); eW[3] = fexp2(0.0f - cv3 - Sf);
            }
            float a0 = pW[0], a1 = pW[1], a2 = pW[2], a3 = pW[3];
            float a4 = pW[4], a5 = pW[5], a6 = pW[6], a7 = pW[7];
            float dg = luW; float eR[RQ];
#pragma unroll
            for (int r = 0; r < RQ; ++r) {
                const float4 d0 = ld[slot][r][0]; const float4 d1 = ld[slot][r][1];
                float f0 = fexp2(-LOG2E * d0.x), f1 = fexp2(-LOG2E * d0.y);
                float f2 = fexp2(-LOG2E * d0.z), f3 = fexp2(-LOG2E * d0.w);
                float f4 = fexp2(-LOG2E * d1.x), f5 = fexp2(-LOG2E * d1.y);
                float f6 = fexp2(-LOG2E * d1.z), f7 = fexp2(-LOG2E * d1.w);
                float s01 = a0 + a1, s12 = a1 + a2, s23 = a2 + a3, s34 = a3 + a4;
                float s45 = a4 + a5, s56 = a5 + a6, s67 = a6 + a7;
                float t0 = dg + eW[r];
                float W0 = f0 * (a0 + t0); float W1 = f1 * (s01 + W0);
                float W2 = f2 * (s12 + W1); float W3 = f3 * (s23 + W2);
                float W4 = f4 * (s34 + W3); float W5 = f5 * (s45 + W4);
                float W6 = f6 * (s56 + W5); float W7 = f7 * (s67 + W6);
                eR[r] = W7; dg = eW[r];
                a0 = W0; a1 = W1; a2 = W2; a3 = W3; a4 = W4; a5 = W5; a6 = W6; a7 = W7;
            }
            const int e = ffrexpe(a7); const float sc = fldexp(1.0f, -e);
            if (active) {
                pW[0] = a0 * sc; pW[1] = a1 * sc; pW[2] = a2 * sc; pW[3] = a3 * sc;
                pW[4] = a4 * sc; pW[5] = a5 * sc; pW[6] = a6 * sc; pW[7] = a7 * sc;
                luW = dg * sc;
                exW[0] = eR[0] * sc; exW[1] = eR[1] * sc; exW[2] = eR[2] * sc; exW[3] = eR[3] * sc;
                S += e; exS = S;
            }
            if (isProd && active) {
                const float Sf = (float)S;
                float v0 = 0.0f - (flog2(exW[0]) + Sf), v1 = 0.0f - (flog2(exW[1]) + Sf);
                float v2 = 0.0f - (flog2(exW[2]) + Sf), v3 = 0.0f - (flog2(exW[3]) + Sf);
                __hip_atomic_store(&pay[base + (size_t)p * 2 + 0], packv(v0, v1), __ATOMIC_RELAXED, __HIP_MEMORY_SCOPE_AGENT);
                __hip_atomic_store(&pay[base + (size_t)p * 2 + 1], packv(v2, v3), __ATOMIC_RELAXED, __HIP_MEMORY_SCOPE_AGENT);
            }
            { int pc = min(max(p + 2, 0), NQ - 1);
              const float* a = bp + (size_t)(pc * RQ) * N;
#pragma unroll
              for (int r = 0; r < RQ; ++r) { ld[slot][r][0] = *(const float4*)(a + (size_t)r * N); ld[slot][r][1] = *(const float4*)(a + (size_t)r * N + 4); } }
            __builtin_amdgcn_sched_barrier(0);
            if (isCons && (p + 8) < NQ) {
                rg[u][0] = ldrelax(&pay[base + (size_t)(p + 8) * 2 + 0]);
                rg[u][1] = ldrelax(&pay[base + (size_t)(p + 8) * 2 + 1]);
            }
            nW[0] = __shfl_up(exW[0], 1); nW[1] = __shfl_up(exW[1], 1);
            nW[2] = __shfl_up(exW[2], 1); nW[3] = __shfl_up(exW[3], 1);
            nS = __shfl_up(exS, 1);
        }
    }
    if (q == NPAN - 1 && t == TPB - 1)
        out[b] = -(flog2(pW[KC - 1]) + (float)S) * LN2;
}

extern "C" void kernel_launch(void* const* d_in, const int* in_sizes, int n_in,
                              void* d_out, int out_size, void* d_ws, size_t ws_size,
                              hipStream_t stream) {
    const float* D = (const float*)d_in[0];
    float* out = (float*)d_out;
    const int B = in_sizes[0] / (N * N);

    unsigned long long* pay = (unsigned long long*)d_ws;
    hipMemsetAsync(d_ws, 0xFF, MBOX_BYTES, stream);

    if (ws_size >= MBOX_BYTES + DP_BYTES && B == 64) {
        float* Dp = (float*)((char*)d_ws + MBOX_BYTES);
        prepass_kernel<<<128 * 16 * 8, 256, 0, stream>>>(D, Dp);
        softdtw_kernel<<<B * NPAN, TPB, 0, stream>>>(Dp, out, pay);
    } else {
        softdtw_fb<<<B * NPAN, TPB, 0, stream>>>(D, out, pay);
    }
}

// Round 24
// 294.831 us; speedup vs baseline: 1.2574x; 1.2574x over previous
//
#include <hip/hip_runtime.h>

// Soft-DTW, gamma=1.0, B=64, N=M=1024. Linear-weight cells + integer-exponent
// scale tracking (R15-R20 numerics, proven absmax 0.0).
// R24 = R20 with RQ=8 (8 rows per iteration). Rationale: R14/R16/R20/R22/R23
// all show T_iter ~= 1500-1650 cyc regardless of cell count (16 vs 32),
// memory pattern (scattered vs coalesced), or in-loop transcendentals
// (32 exp2 vs 0) -> per-iteration cost is FIXED overhead (inter-iteration
// serial spine). So amortize it: ITER 320->192, effective ~390->~255.
// All protocol R20-verbatim: NPAN=2 panels, poison mailbox (4 u64/quad now),
// 8-deep static-indexed consumer prefetch ring, plain-load D ring (2 slots),
// pipelined __shfl_up handoff, integer-exponent renorm via frexp/ldexp.

#define LOG2E 1.4426950408889634f
#define LN2  0.6931471805599453f

constexpr int N = 1024;
constexpr int TPB = 64;              // one wave per block
constexpr int KC = 8;                // columns per thread (panel = 512 cols)
constexpr int RQ = 8;                // rows per iteration
constexpr int NQ = N / RQ;           // 128 quads
constexpr int NPAN = 2;
constexpr int PC = N / NPAN;         // 512 columns per panel
constexpr int ITER = 192;            // last real iteration: 127 + 63 = 190
constexpr unsigned long long POISON = 0xFFFFFFFFFFFFFFFFull;

__device__ __forceinline__ float fexp2(float x){float r;asm("v_exp_f32 %0, %1":"=v"(r):"v"(x));return r;}
__device__ __forceinline__ float flog2(float x){float r;asm("v_log_f32 %0, %1":"=v"(r):"v"(x));return r;}
__device__ __forceinline__ int   ffrexpe(float x){int r;asm("v_frexp_exp_i32_f32 %0, %1":"=v"(r):"v"(x));return r;}
__device__ __forceinline__ float fldexp(float x, int e){float r;asm("v_ldexp_f32 %0, %1, %2":"=v"(r):"v"(x),"v"(e));return r;}
__device__ __forceinline__ unsigned long long packv(float a, float b){
    return ((unsigned long long)__float_as_uint(b) << 32) | __float_as_uint(a);
}
__device__ __forceinline__ unsigned long long ldrelax(const unsigned long long* p){
    return __hip_atomic_load(p, __ATOMIC_RELAXED, __HIP_MEMORY_SCOPE_AGENT);
}

__global__ __launch_bounds__(TPB, 1)
void softdtw_kernel(const float* __restrict__ D, float* __restrict__ out,
                    unsigned long long* __restrict__ pay){
    const int blk = blockIdx.x;
    const int b = blk & 63;              // batch
    const int q = blk >> 6;              // panel (0 or 1)
    const int t = threadIdx.x;
    const float* __restrict__ bp = D + (size_t)b * N * N + q * PC + t * KC;

    const bool isProd = (t == TPB - 1) && (q == 0);
    const bool isCons = (t == 0) && (q == 1);
    const size_t base = (size_t)b * NQ * 4;   // 4 u64 words per quad

    float pW[KC] = {0,0,0,0,0,0,0,0};
    int   S = 0;                          // scale: W_true = W * 2^S
    float luW = (t == 0 && q == 0) ? 1.0f : 0.0f;
    float exW[RQ] = {0,0,0,0,0,0,0,0};
    int   exS = 0;
    float nW[RQ] = {0,0,0,0,0,0,0,0};
    int   nS = 0;

    // consumer prefetch ring: quad j served from slot j&7 (static indexing)
    unsigned long long rg[8][4];
#pragma unroll
    for (int i = 0; i < 8; ++i)
#pragma unroll
        for (int k = 0; k < 4; ++k) rg[i][k] = POISON;
    if (isCons) {
#pragma unroll
        for (int i = 0; i < 8; ++i)
#pragma unroll
            for (int k = 0; k < 4; ++k)
                rg[i][k] = ldrelax(&pay[base + (size_t)i * 4 + k]);
    }

    float4 ld[2][RQ][2];                 // D ring: 2 slots x 8 rows x 32B
#pragma unroll
    for (int x = 0; x < 2; ++x) {
        int pc = min(max(x - t, 0), NQ - 1);
        const float* a = bp + (size_t)(pc * RQ) * N;
#pragma unroll
        for (int r = 0; r < RQ; ++r) {
            ld[x][r][0] = *(const float4*)(a + (size_t)r * N);
            ld[x][r][1] = *(const float4*)(a + (size_t)r * N + 4);
        }
    }
    __builtin_amdgcn_sched_barrier(0);

    for (int jb = 0; jb < ITER; jb += 8) {
#pragma unroll
        for (int u = 0; u < 8; ++u) {
            const int p = jb + u - t;
            const bool active = (unsigned)p < (unsigned)NQ;
            const int slot = u & 1;

            // ---- consumer: validate + decode quad p (t=0 so p==jb+u, slot u) ----
            float cv[RQ];
#pragma unroll
            for (int r = 0; r < RQ; ++r) cv[r] = 0.0f;
            if (isCons && active) {
                unsigned long long w0 = rg[u][0], w1 = rg[u][1];
                unsigned long long w2 = rg[u][2], w3 = rg[u][3];
                while (w0 == POISON) w0 = ldrelax(&pay[base + (size_t)p * 4 + 0]);
                while (w1 == POISON) w1 = ldrelax(&pay[base + (size_t)p * 4 + 1]);
                while (w2 == POISON) w2 = ldrelax(&pay[base + (size_t)p * 4 + 2]);
                while (w3 == POISON) w3 = ldrelax(&pay[base + (size_t)p * 4 + 3]);
                cv[0] = __uint_as_float((unsigned)(w0 & 0xFFFFFFFFu));
                cv[1] = __uint_as_float((unsigned)(w0 >> 32));
                cv[2] = __uint_as_float((unsigned)(w1 & 0xFFFFFFFFu));
                cv[3] = __uint_as_float((unsigned)(w1 >> 32));
                cv[4] = __uint_as_float((unsigned)(w2 & 0xFFFFFFFFu));
                cv[5] = __uint_as_float((unsigned)(w2 >> 32));
                cv[6] = __uint_as_float((unsigned)(w3 & 0xFFFFFFFFu));
                cv[7] = __uint_as_float((unsigned)(w3 >> 32));
            }

            // ---- anchor my scale at my first quad ----
            const int iS = nS;
            if (p == 0) {
                if (isCons) S = (int)(0.0f - cv[0]);
                else if (t == 0 && q == 0) S = 0;
                else S = iS;
            }

            // ---- incoming left edges in my scale ----
            float eW[RQ];
            {
                const int dS = iS - S;
#pragma unroll
                for (int r = 0; r < RQ; ++r) eW[r] = fldexp(nW[r], dS);
            }
            if (t == 0 && q == 0) {
#pragma unroll
                for (int r = 0; r < RQ; ++r) eW[r] = 0.0f;
            }
            if (isCons) {
                const float Sf = (float)S;
#pragma unroll
                for (int r = 0; r < RQ; ++r) eW[r] = fexp2(0.0f - cv[r] - Sf);
            }

            // ---- 64 cells: W = f*(up + diag + left), 8 rows x 8 cols ----
            float a0 = pW[0], a1 = pW[1], a2 = pW[2], a3 = pW[3];
            float a4 = pW[4], a5 = pW[5], a6 = pW[6], a7 = pW[7];
            float dg = luW;
            float eR[RQ];
#pragma unroll
            for (int r = 0; r < RQ; ++r) {
                const float4 d0 = ld[slot][r][0];
                const float4 d1 = ld[slot][r][1];
                float f0 = fexp2(-LOG2E * d0.x), f1 = fexp2(-LOG2E * d0.y);
                float f2 = fexp2(-LOG2E * d0.z), f3 = fexp2(-LOG2E * d0.w);
                float f4 = fexp2(-LOG2E * d1.x), f5 = fexp2(-LOG2E * d1.y);
                float f6 = fexp2(-LOG2E * d1.z), f7 = fexp2(-LOG2E * d1.w);
                float s01 = a0 + a1, s12 = a1 + a2, s23 = a2 + a3, s34 = a3 + a4;
                float s45 = a4 + a5, s56 = a5 + a6, s67 = a6 + a7;
                float t0 = dg + eW[r];
                float W0 = f0 * (a0 + t0);
                float W1 = f1 * (s01 + W0);
                float W2 = f2 * (s12 + W1);
                float W3 = f3 * (s23 + W2);
                float W4 = f4 * (s34 + W3);
                float W5 = f5 * (s45 + W4);
                float W6 = f6 * (s56 + W5);
                float W7 = f7 * (s67 + W6);
                eR[r] = W7;
                dg = eW[r];
                a0 = W0; a1 = W1; a2 = W2; a3 = W3;
                a4 = W4; a5 = W5; a6 = W6; a7 = W7;
            }

            const int e = ffrexpe(a7);
            const float sc = fldexp(1.0f, -e);

            if (active) {                  // masked commit
                pW[0] = a0 * sc; pW[1] = a1 * sc; pW[2] = a2 * sc; pW[3] = a3 * sc;
                pW[4] = a4 * sc; pW[5] = a5 * sc; pW[6] = a6 * sc; pW[7] = a7 * sc;
                luW = dg * sc;
#pragma unroll
                for (int r = 0; r < RQ; ++r) exW[r] = eR[r] * sc;
                S += e; exS = S;
            }

            // ---- producer: publish quad p (normalized v-form, relaxed u64) ----
            if (isProd && active) {
                const float Sf = (float)S;
                float v0 = 0.0f - (flog2(exW[0]) + Sf);
                float v1 = 0.0f - (flog2(exW[1]) + Sf);
                float v2 = 0.0f - (flog2(exW[2]) + Sf);
                float v3 = 0.0f - (flog2(exW[3]) + Sf);
                float v4 = 0.0f - (flog2(exW[4]) + Sf);
                float v5 = 0.0f - (flog2(exW[5]) + Sf);
                float v6 = 0.0f - (flog2(exW[6]) + Sf);
                float v7 = 0.0f - (flog2(exW[7]) + Sf);
                __hip_atomic_store(&pay[base + (size_t)p * 4 + 0], packv(v0, v1), __ATOMIC_RELAXED, __HIP_MEMORY_SCOPE_AGENT);
                __hip_atomic_store(&pay[base + (size_t)p * 4 + 1], packv(v2, v3), __ATOMIC_RELAXED, __HIP_MEMORY_SCOPE_AGENT);
                __hip_atomic_store(&pay[base + (size_t)p * 4 + 2], packv(v4, v5), __ATOMIC_RELAXED, __HIP_MEMORY_SCOPE_AGENT);
                __hip_atomic_store(&pay[base + (size_t)p * 4 + 3], packv(v6, v7), __ATOMIC_RELAXED, __HIP_MEMORY_SCOPE_AGENT);
            }

            // ---- D loads for iteration j+2 into the consumed slot ----
            {
                int pc = min(max(p + 2, 0), NQ - 1);
                const float* a = bp + (size_t)(pc * RQ) * N;
#pragma unroll
                for (int r = 0; r < RQ; ++r) {
                    ld[slot][r][0] = *(const float4*)(a + (size_t)r * N);
                    ld[slot][r][1] = *(const float4*)(a + (size_t)r * N + 4);
                }
            }
            __builtin_amdgcn_sched_barrier(0);

            // ---- consumer: prefetch quad p+8 into ring slot u (used at j+8) ----
            if (isCons && (p + 8) < NQ) {
#pragma unroll
                for (int k = 0; k < 4; ++k)
                    rg[u][k] = ldrelax(&pay[base + (size_t)(p + 8) * 4 + k]);
            }

            // ---- pipelined intra-wave handoff ----
#pragma unroll
            for (int r = 0; r < RQ; ++r) nW[r] = __shfl_up(exW[r], 1);
            nS = __shfl_up(exS, 1);
        }
    }

    // cost = -(log2(W) + S) * ln2  (panel 1, thread 63, last quad)
    if (q == NPAN - 1 && t == TPB - 1)
        out[b] = -(flog2(pW[KC - 1]) + (float)S) * LN2;
}

extern "C" void kernel_launch(void* const* d_in, const int* in_sizes, int n_in,
                              void* d_out, int out_size, void* d_ws, size_t ws_size,
                              hipStream_t stream) {
    const float* D = (const float*)d_in[0];
    float* out = (float*)d_out;
    const int B = in_sizes[0] / (N * N);

    unsigned long long* pay = (unsigned long long*)d_ws;
    const size_t payBytes = (size_t)B * NQ * 4 * sizeof(unsigned long long);

    // poison the mailbox each launch (graph-capturable async memset)
    hipMemsetAsync(d_ws, 0xFF, payBytes, stream);

    softdtw_kernel<<<B * NPAN, TPB, 0, stream>>>(D, out, pay);
}